// Round 2
// baseline (11185.621 us; speedup 1.0000x reference)
//
#include <hip/hip_runtime.h>

// ---------------------------------------------------------------- copy x -> h
__global__ __launch_bounds__(256) void copy_f32(const float* __restrict__ x,
                                                float* __restrict__ h, int n) {
    int i = blockIdx.x * 256 + threadIdx.x;
    if (i < n) h[i] = x[i];
}

// ---------------------------------------------------------------- LayerNorm (1024-wide rows)
__global__ __launch_bounds__(256) void ln_kernel(const float* __restrict__ in,
                                                 const float* __restrict__ w,
                                                 const float* __restrict__ b,
                                                 float* __restrict__ out) {
    int row = blockIdx.x, tid = threadIdx.x;
    const float* x = in + (size_t)row * 1024;
    float v[4], s = 0.f, ss = 0.f;
#pragma unroll
    for (int i = 0; i < 4; i++) {
        v[i] = x[tid + i * 256];
        s += v[i];
        ss += v[i] * v[i];
    }
#pragma unroll
    for (int off = 32; off >= 1; off >>= 1) {
        s  += __shfl_xor(s, off, 64);
        ss += __shfl_xor(ss, off, 64);
    }
    __shared__ float ps[4], pss[4];
    int wid = tid >> 6, lane = tid & 63;
    if (lane == 0) { ps[wid] = s; pss[wid] = ss; }
    __syncthreads();
    s  = ps[0] + ps[1] + ps[2] + ps[3];
    ss = pss[0] + pss[1] + pss[2] + pss[3];
    float mean = s * (1.f / 1024.f);
    float var  = ss * (1.f / 1024.f) - mean * mean;
    float rstd = rsqrtf(var + 1e-5f);
    float* y = out + (size_t)row * 1024;
#pragma unroll
    for (int i = 0; i < 4; i++) {
        int c = tid + i * 256;
        y[c] = (v[i] - mean) * rstd * w[c] + b[c];
    }
}

// ---------------------------------------------------------------- fp32 tiled GEMM
// C[M,N] = act( A[M,K] @ W[K,N] + bias ) (+ resid). All fp32.
// 64x64 tile, BK=16, 256 threads, 4x4 micro-tile per thread.
template <bool GELU_ACT, bool RESID>
__global__ __launch_bounds__(256) void gemm_kernel(const float* __restrict__ A,
                                                   const float* __restrict__ W,
                                                   const float* __restrict__ bias,
                                                   const float* __restrict__ resid,
                                                   float* __restrict__ C,
                                                   int M, int N, int K) {
    __shared__ __align__(16) float As[16][68];  // [k][m] (68*4B = 272 = 17*16 -> rows stay 16B-aligned)
    __shared__ __align__(16) float Bs[16][68];  // [k][n]
    int tid = threadIdx.x;
    int tx = tid & 15, ty = tid >> 4;
    int row0 = blockIdx.y * 64, col0 = blockIdx.x * 64;
    int ar = tid >> 4, acol = tid & 15;  // A loader
    int br = tid >> 6, bc = tid & 63;    // W loader
    float acc[4][4] = {{0.f}};

    for (int k0 = 0; k0 < K; k0 += 16) {
#pragma unroll
        for (int i = 0; i < 4; i++)
            As[acol][ar + i * 16] = A[(size_t)(row0 + ar + i * 16) * K + k0 + acol];
#pragma unroll
        for (int i = 0; i < 4; i++)
            Bs[br + i * 4][bc] = W[(size_t)(k0 + br + i * 4) * N + col0 + bc];
        __syncthreads();
#pragma unroll
        for (int k = 0; k < 16; k++) {
            float4 a4 = *(const float4*)&As[k][ty * 4];
            float4 b4 = *(const float4*)&Bs[k][tx * 4];
            float a[4] = {a4.x, a4.y, a4.z, a4.w};
            float bb[4] = {b4.x, b4.y, b4.z, b4.w};
#pragma unroll
            for (int i = 0; i < 4; i++)
#pragma unroll
                for (int j = 0; j < 4; j++) acc[i][j] += a[i] * bb[j];
        }
        __syncthreads();
    }
#pragma unroll
    for (int i = 0; i < 4; i++) {
        int r = row0 + ty * 4 + i;
#pragma unroll
        for (int j = 0; j < 4; j++) {
            int c = col0 + tx * 4 + j;
            float v = acc[i][j] + bias[c];
            if (GELU_ACT) v = 0.5f * v * (1.f + erff(v * 0.70710678118f));
            if (RESID) v += resid[(size_t)r * N + c];
            C[(size_t)r * N + c] = v;
        }
    }
}

// ---------------------------------------------------------------- causal attention
// One wave per (q, h, b). qkv fp32 [B*S, 3072]: q | k | v each 1024 ch, head h at h*64.
// Online softmax over key chunks of 64; K chunk staged in LDS, V read coalesced.
__global__ __launch_bounds__(64) void attn_kernel(const float* __restrict__ qkv,
                                                  float* __restrict__ o) {
    const int S = 1024;
    int q = blockIdx.x, h = blockIdx.y, b = blockIdx.z;
    int lane = threadIdx.x;

    __shared__ float qs[64];
    __shared__ float Ks[64][65];
    __shared__ float ps[64];

    const float* base  = qkv + (size_t)b * S * 3072;
    const float* kbase = base + 1024 + h * 64;
    const float* vbase = base + 2048 + h * 64;

    qs[lane] = base[(size_t)q * 3072 + h * 64 + lane] * 0.125f;  // scale = HD^-0.5
    __syncthreads();

    float m = -1e30f, l = 0.f, acc = 0.f;
    int nchunk = q / 64 + 1;
    for (int c = 0; c < nchunk; ++c) {
        int k0 = c * 64;
        for (int r = 0; r < 64; ++r)
            Ks[r][lane] = kbase[(size_t)(k0 + r) * 3072 + lane];
        __syncthreads();

        int key = k0 + lane;
        float sv = -1e30f;
        if (key <= q) {
            float t = 0.f;
#pragma unroll 16
            for (int d = 0; d < 64; ++d) t += qs[d] * Ks[lane][d];
            sv = t;
        }
        float cm = sv;
#pragma unroll
        for (int off = 32; off >= 1; off >>= 1) cm = fmaxf(cm, __shfl_xor(cm, off, 64));
        float m_new = fmaxf(m, cm);
        float p = (key <= q) ? __expf(sv - m_new) : 0.f;
        float sp = p;
#pragma unroll
        for (int off = 32; off >= 1; off >>= 1) sp += __shfl_xor(sp, off, 64);
        float alpha = __expf(m - m_new);
        l = l * alpha + sp;
        ps[lane] = p;
        __syncthreads();
        float a2 = 0.f;
#pragma unroll 8
        for (int k = 0; k < 64; ++k)
            a2 += ps[k] * vbase[(size_t)(k0 + k) * 3072 + lane];
        acc = acc * alpha + a2;
        m = m_new;
        __syncthreads();
    }
    o[((size_t)b * S + q) * 1024 + h * 64 + lane] = acc / l;
}

// ---------------------------------------------------------------- final projection to WIN=5
__global__ __launch_bounds__(64) void proj_kernel(const float* __restrict__ hn,
                                                  const float* __restrict__ Wp,
                                                  const float* __restrict__ bp,
                                                  float* __restrict__ out) {
    int t = blockIdx.x, lane = threadIdx.x;
    const float* x = hn + (size_t)t * 1024;
    float acc[5] = {0.f, 0.f, 0.f, 0.f, 0.f};
    for (int d = lane; d < 1024; d += 64) {
        float xv = x[d];
#pragma unroll
        for (int j = 0; j < 5; j++) acc[j] += xv * Wp[d * 5 + j];
    }
#pragma unroll
    for (int j = 0; j < 5; j++)
#pragma unroll
        for (int off = 32; off >= 1; off >>= 1) acc[j] += __shfl_xor(acc[j], off, 64);
    if (lane == 0) {
#pragma unroll
        for (int j = 0; j < 5; j++)
            out[(size_t)t * 5 + j] = acc[j] + bp[j];
    }
}

// ---------------------------------------------------------------- launch
extern "C" void kernel_launch(void* const* d_in, const int* in_sizes, int n_in,
                              void* d_out, int out_size, void* d_ws, size_t ws_size,
                              hipStream_t stream) {
    const float* x    = (const float*)d_in[0];
    const float* Wqkv = (const float*)d_in[1];
    const float* bqkv = (const float*)d_in[2];
    const float* Wo   = (const float*)d_in[3];
    const float* bo   = (const float*)d_in[4];
    const float* ln1w = (const float*)d_in[5];
    const float* ln1b = (const float*)d_in[6];
    const float* W1   = (const float*)d_in[7];
    const float* b1   = (const float*)d_in[8];
    const float* W2   = (const float*)d_in[9];
    const float* b2   = (const float*)d_in[10];
    const float* ln2w = (const float*)d_in[11];
    const float* ln2b = (const float*)d_in[12];
    const float* lnfw = (const float*)d_in[13];
    const float* lnfb = (const float*)d_in[14];
    const float* Wp   = (const float*)d_in[15];
    const float* bp   = (const float*)d_in[16];
    float* out = (float*)d_out;

    // fp32 workspace layout (~59 MB): buf holds qkv (24 MB) then ff (32 MB) —
    // qkv is dead after attention + Wo projection, so they alias safely.
    float* h   = (float*)d_ws;          // 2048*1024
    float* hn  = h   + 2097152;         // 2048*1024
    float* buf = hn  + 2097152;         // 2048*4096 (qkv uses first 2048*3072)
    float* o   = buf + 8388608;         // 2048*1024

    copy_f32<<<8192, 256, 0, stream>>>(x, h, 2097152);

    for (int l = 0; l < 6; ++l) {
        float* qkv = buf;
        float* ff  = buf;
        ln_kernel<<<2048, 256, 0, stream>>>(h, ln1w + l * 1024, ln1b + l * 1024, hn);
        gemm_kernel<false, false><<<dim3(48, 32), 256, 0, stream>>>(
            hn, Wqkv + (size_t)l * 1024 * 3072, bqkv + l * 3072, nullptr, qkv,
            2048, 3072, 1024);
        attn_kernel<<<dim3(1024, 16, 2), 64, 0, stream>>>(qkv, o);
        gemm_kernel<false, true><<<dim3(16, 32), 256, 0, stream>>>(
            o, Wo + (size_t)l * 1024 * 1024, bo + l * 1024, h, h,
            2048, 1024, 1024);
        ln_kernel<<<2048, 256, 0, stream>>>(h, ln2w + l * 1024, ln2b + l * 1024, hn);
        gemm_kernel<true, false><<<dim3(64, 32), 256, 0, stream>>>(
            hn, W1 + (size_t)l * 1024 * 4096, b1 + l * 4096, nullptr, ff,
            2048, 4096, 1024);
        gemm_kernel<false, true><<<dim3(16, 32), 256, 0, stream>>>(
            ff, W2 + (size_t)l * 4096 * 1024, b2 + l * 1024, h, h,
            2048, 1024, 4096);
    }
    ln_kernel<<<2048, 256, 0, stream>>>(h, lnfw, lnfb, hn);
    proj_kernel<<<2048, 64, 0, stream>>>(hn, Wp, bp, out);
}

// Round 3
// 5794.078 us; speedup vs baseline: 1.9305x; 1.9305x over previous
//
#include <hip/hip_runtime.h>

// ---------------------------------------------------------------- copy x -> h
__global__ __launch_bounds__(256) void copy_f32(const float* __restrict__ x,
                                                float* __restrict__ h, int n) {
    int i = blockIdx.x * 256 + threadIdx.x;
    if (i < n) h[i] = x[i];
}

// ---------------------------------------------------------------- LayerNorm (1024-wide rows)
__global__ __launch_bounds__(256) void ln_kernel(const float* __restrict__ in,
                                                 const float* __restrict__ w,
                                                 const float* __restrict__ b,
                                                 float* __restrict__ out) {
    int row = blockIdx.x, tid = threadIdx.x;
    const float* x = in + (size_t)row * 1024;
    float v[4], s = 0.f, ss = 0.f;
#pragma unroll
    for (int i = 0; i < 4; i++) {
        v[i] = x[tid + i * 256];
        s += v[i];
        ss += v[i] * v[i];
    }
#pragma unroll
    for (int off = 32; off >= 1; off >>= 1) {
        s  += __shfl_xor(s, off, 64);
        ss += __shfl_xor(ss, off, 64);
    }
    __shared__ float ps[4], pss[4];
    int wid = tid >> 6, lane = tid & 63;
    if (lane == 0) { ps[wid] = s; pss[wid] = ss; }
    __syncthreads();
    s  = ps[0] + ps[1] + ps[2] + ps[3];
    ss = pss[0] + pss[1] + pss[2] + pss[3];
    float mean = s * (1.f / 1024.f);
    float var  = ss * (1.f / 1024.f) - mean * mean;
    float rstd = rsqrtf(var + 1e-5f);
    float* y = out + (size_t)row * 1024;
#pragma unroll
    for (int i = 0; i < 4; i++) {
        int c = tid + i * 256;
        y[c] = (v[i] - mean) * rstd * w[c] + b[c];
    }
}

// ---------------------------------------------------------------- fp32 tiled GEMM
// C[M,N] = act( A[M,K] @ W[K,N] + bias ) (+ resid). All fp32.
// 64x64 tile, BK=16, 256 threads, 4x4 micro-tile per thread.
template <bool GELU_ACT, bool RESID>
__global__ __launch_bounds__(256) void gemm_kernel(const float* __restrict__ A,
                                                   const float* __restrict__ W,
                                                   const float* __restrict__ bias,
                                                   const float* __restrict__ resid,
                                                   float* __restrict__ C,
                                                   int M, int N, int K) {
    __shared__ __align__(16) float As[16][68];
    __shared__ __align__(16) float Bs[16][68];
    int tid = threadIdx.x;
    int tx = tid & 15, ty = tid >> 4;
    int row0 = blockIdx.y * 64, col0 = blockIdx.x * 64;
    int ar = tid >> 4, acol = tid & 15;
    int br = tid >> 6, bc = tid & 63;
    float acc[4][4] = {{0.f}};

    for (int k0 = 0; k0 < K; k0 += 16) {
#pragma unroll
        for (int i = 0; i < 4; i++)
            As[acol][ar + i * 16] = A[(size_t)(row0 + ar + i * 16) * K + k0 + acol];
#pragma unroll
        for (int i = 0; i < 4; i++)
            Bs[br + i * 4][bc] = W[(size_t)(k0 + br + i * 4) * N + col0 + bc];
        __syncthreads();
#pragma unroll
        for (int k = 0; k < 16; k++) {
            float4 a4 = *(const float4*)&As[k][ty * 4];
            float4 b4 = *(const float4*)&Bs[k][tx * 4];
            float a[4] = {a4.x, a4.y, a4.z, a4.w};
            float bb[4] = {b4.x, b4.y, b4.z, b4.w};
#pragma unroll
            for (int i = 0; i < 4; i++)
#pragma unroll
                for (int j = 0; j < 4; j++) acc[i][j] += a[i] * bb[j];
        }
        __syncthreads();
    }
#pragma unroll
    for (int i = 0; i < 4; i++) {
        int r = row0 + ty * 4 + i;
#pragma unroll
        for (int j = 0; j < 4; j++) {
            int c = col0 + tx * 4 + j;
            float v = acc[i][j] + bias[c];
            if (GELU_ACT) v = 0.5f * v * (1.f + erff(v * 0.70710678118f));
            if (RESID) v += resid[(size_t)r * N + c];
            C[(size_t)r * N + c] = v;
        }
    }
}

// ---------------------------------------------------------------- tiled flash attention
// One 256-thread block per (64-query tile, head, batch). Q/K tiles in LDS
// transposed [d][row] for GEMM-style float4 micro-tiles; V direct [k][d];
// P round-trips through LDS. Online softmax state in registers (per 16-lane
// row group). O accumulator in registers (4x4 per thread).
__global__ __launch_bounds__(256) void attn_tile_kernel(const float* __restrict__ qkv,
                                                        float* __restrict__ o) {
    const int S = 1024;
    int bx = blockIdx.x;                 // 0..15
    int h = blockIdx.y, b = blockIdx.z;
    // pair heavy tiles (batch 0, descending) with light tiles (batch 1, ascending)
    int qt = (b == 0) ? (15 - bx) : bx;
    int tid = threadIdx.x;
    int tx = tid & 15, ty = tid >> 4;    // tx: col group, ty: row group

    __shared__ __align__(16) float Qs[64][68];  // [d][q], pre-scaled
    __shared__ __align__(16) float Ks[64][68];  // [d][k]
    __shared__ __align__(16) float Vs[64][68];  // [k][d]
    __shared__ __align__(16) float Ps[64][68];  // [k][q]

    const float* base = qkv + (size_t)b * S * 3072 + h * 64;
    const float* qb = base;
    const float* kb = base + 1024;
    const float* vb = base + 2048;
    int q0 = qt * 64;

    // load Q tile (scaled by HD^-0.5), transposed
#pragma unroll
    for (int it = 0; it < 4; ++it) {
        int r = it * 16 + ty;
        float4 v = *(const float4*)&qb[(size_t)(q0 + r) * 3072 + tx * 4];
        Qs[tx * 4 + 0][r] = v.x * 0.125f;
        Qs[tx * 4 + 1][r] = v.y * 0.125f;
        Qs[tx * 4 + 2][r] = v.z * 0.125f;
        Qs[tx * 4 + 3][r] = v.w * 0.125f;
    }

    float m_i[4], l_i[4], O[4][4];
#pragma unroll
    for (int i = 0; i < 4; i++) {
        m_i[i] = -1e30f; l_i[i] = 0.f;
#pragma unroll
        for (int j = 0; j < 4; j++) O[i][j] = 0.f;
    }

    for (int c = 0; c <= qt; ++c) {
        int k0 = c * 64;
        __syncthreads();  // previous iteration's Vs/Ps reads done
#pragma unroll
        for (int it = 0; it < 4; ++it) {
            int r = it * 16 + ty;
            float4 kv = *(const float4*)&kb[(size_t)(k0 + r) * 3072 + tx * 4];
            Ks[tx * 4 + 0][r] = kv.x;
            Ks[tx * 4 + 1][r] = kv.y;
            Ks[tx * 4 + 2][r] = kv.z;
            Ks[tx * 4 + 3][r] = kv.w;
            float4 vv = *(const float4*)&vb[(size_t)(k0 + r) * 3072 + tx * 4];
            *(float4*)&Vs[r][tx * 4] = vv;
        }
        __syncthreads();

        // scores: s[i][j] = sum_d Qs[d][ty*4+i] * Ks[d][tx*4+j]
        float s[4][4] = {{0.f}};
#pragma unroll 16
        for (int d = 0; d < 64; ++d) {
            float4 a4 = *(const float4*)&Qs[d][ty * 4];
            float4 b4 = *(const float4*)&Ks[d][tx * 4];
            float a[4] = {a4.x, a4.y, a4.z, a4.w};
            float bb[4] = {b4.x, b4.y, b4.z, b4.w};
#pragma unroll
            for (int i = 0; i < 4; i++)
#pragma unroll
                for (int j = 0; j < 4; j++) s[i][j] += a[i] * bb[j];
        }
        // causal mask on diagonal tile
        if (c == qt) {
#pragma unroll
            for (int i = 0; i < 4; i++)
#pragma unroll
                for (int j = 0; j < 4; j++)
                    if (tx * 4 + j > ty * 4 + i) s[i][j] = -1e30f;
        }
        // online softmax per row (16-lane group shares rows -> shfl over 16)
        float alpha[4], p[4][4];
#pragma unroll
        for (int i = 0; i < 4; i++) {
            float mx = fmaxf(fmaxf(s[i][0], s[i][1]), fmaxf(s[i][2], s[i][3]));
#pragma unroll
            for (int off = 8; off >= 1; off >>= 1) mx = fmaxf(mx, __shfl_xor(mx, off, 64));
            float mnew = fmaxf(m_i[i], mx);
            alpha[i] = __expf(m_i[i] - mnew);
            float rs = 0.f;
#pragma unroll
            for (int j = 0; j < 4; j++) {
                p[i][j] = __expf(s[i][j] - mnew);
                if (s[i][j] <= -1e29f) p[i][j] = 0.f;
                rs += p[i][j];
            }
#pragma unroll
            for (int off = 8; off >= 1; off >>= 1) rs += __shfl_xor(rs, off, 64);
            l_i[i] = l_i[i] * alpha[i] + rs;
            m_i[i] = mnew;
        }
        // P -> LDS (transposed [k][q]); scale O by alpha
#pragma unroll
        for (int i = 0; i < 4; i++)
#pragma unroll
            for (int j = 0; j < 4; j++)
                Ps[tx * 4 + j][ty * 4 + i] = p[i][j];
#pragma unroll
        for (int i = 0; i < 4; i++)
#pragma unroll
            for (int j = 0; j < 4; j++) O[i][j] *= alpha[i];
        __syncthreads();
        // PV: O[i][j] += sum_k Ps[k][ty*4+i] * Vs[k][tx*4+j]
#pragma unroll 16
        for (int k = 0; k < 64; ++k) {
            float4 a4 = *(const float4*)&Ps[k][ty * 4];
            float4 b4 = *(const float4*)&Vs[k][tx * 4];
            float a[4] = {a4.x, a4.y, a4.z, a4.w};
            float bb[4] = {b4.x, b4.y, b4.z, b4.w};
#pragma unroll
            for (int i = 0; i < 4; i++)
#pragma unroll
                for (int j = 0; j < 4; j++) O[i][j] += a[i] * bb[j];
        }
    }

    // epilogue: normalize and store
#pragma unroll
    for (int i = 0; i < 4; i++) {
        float inv = 1.f / l_i[i];
        int q = q0 + ty * 4 + i;
        float4 v = make_float4(O[i][0] * inv, O[i][1] * inv, O[i][2] * inv, O[i][3] * inv);
        *(float4*)&o[((size_t)b * S + q) * 1024 + h * 64 + tx * 4] = v;
    }
}

// ---------------------------------------------------------------- final projection to WIN=5
__global__ __launch_bounds__(64) void proj_kernel(const float* __restrict__ hn,
                                                  const float* __restrict__ Wp,
                                                  const float* __restrict__ bp,
                                                  float* __restrict__ out) {
    int t = blockIdx.x, lane = threadIdx.x;
    const float* x = hn + (size_t)t * 1024;
    float acc[5] = {0.f, 0.f, 0.f, 0.f, 0.f};
    for (int d = lane; d < 1024; d += 64) {
        float xv = x[d];
#pragma unroll
        for (int j = 0; j < 5; j++) acc[j] += xv * Wp[d * 5 + j];
    }
#pragma unroll
    for (int j = 0; j < 5; j++)
#pragma unroll
        for (int off = 32; off >= 1; off >>= 1) acc[j] += __shfl_xor(acc[j], off, 64);
    if (lane == 0) {
#pragma unroll
        for (int j = 0; j < 5; j++)
            out[(size_t)t * 5 + j] = acc[j] + bp[j];
    }
}

// ---------------------------------------------------------------- launch
extern "C" void kernel_launch(void* const* d_in, const int* in_sizes, int n_in,
                              void* d_out, int out_size, void* d_ws, size_t ws_size,
                              hipStream_t stream) {
    const float* x    = (const float*)d_in[0];
    const float* Wqkv = (const float*)d_in[1];
    const float* bqkv = (const float*)d_in[2];
    const float* Wo   = (const float*)d_in[3];
    const float* bo   = (const float*)d_in[4];
    const float* ln1w = (const float*)d_in[5];
    const float* ln1b = (const float*)d_in[6];
    const float* W1   = (const float*)d_in[7];
    const float* b1   = (const float*)d_in[8];
    const float* W2   = (const float*)d_in[9];
    const float* b2   = (const float*)d_in[10];
    const float* ln2w = (const float*)d_in[11];
    const float* ln2b = (const float*)d_in[12];
    const float* lnfw = (const float*)d_in[13];
    const float* lnfb = (const float*)d_in[14];
    const float* Wp   = (const float*)d_in[15];
    const float* bp   = (const float*)d_in[16];
    float* out = (float*)d_out;

    float* h   = (float*)d_ws;          // 2048*1024
    float* hn  = h   + 2097152;         // 2048*1024
    float* buf = hn  + 2097152;         // 2048*4096 (qkv uses first 2048*3072; ff aliases)
    float* o   = buf + 8388608;         // 2048*1024

    copy_f32<<<8192, 256, 0, stream>>>(x, h, 2097152);

    for (int l = 0; l < 6; ++l) {
        float* qkv = buf;
        float* ff  = buf;
        ln_kernel<<<2048, 256, 0, stream>>>(h, ln1w + l * 1024, ln1b + l * 1024, hn);
        gemm_kernel<false, false><<<dim3(48, 32), 256, 0, stream>>>(
            hn, Wqkv + (size_t)l * 1024 * 3072, bqkv + l * 3072, nullptr, qkv,
            2048, 3072, 1024);
        attn_tile_kernel<<<dim3(16, 16, 2), 256, 0, stream>>>(qkv, o);
        gemm_kernel<false, true><<<dim3(16, 32), 256, 0, stream>>>(
            o, Wo + (size_t)l * 1024 * 1024, bo + l * 1024, h, h,
            2048, 1024, 1024);
        ln_kernel<<<2048, 256, 0, stream>>>(h, ln2w + l * 1024, ln2b + l * 1024, hn);
        gemm_kernel<true, false><<<dim3(64, 32), 256, 0, stream>>>(
            hn, W1 + (size_t)l * 1024 * 4096, b1 + l * 4096, nullptr, ff,
            2048, 4096, 1024);
        gemm_kernel<false, true><<<dim3(16, 32), 256, 0, stream>>>(
            ff, W2 + (size_t)l * 4096 * 1024, b2 + l * 1024, h, h,
            2048, 1024, 4096);
    }
    ln_kernel<<<2048, 256, 0, stream>>>(h, lnfw, lnfb, hn);
    proj_kernel<<<2048, 64, 0, stream>>>(hn, Wp, bp, out);
}

// Round 4
// 2437.686 us; speedup vs baseline: 4.5886x; 2.3769x over previous
//
#include <hip/hip_runtime.h>

typedef __attribute__((ext_vector_type(8))) __bf16 bf16x8;
typedef __attribute__((ext_vector_type(4))) __bf16 bf16x4;
typedef __attribute__((ext_vector_type(4))) float f32x4;

// ---------------------------------------------------------------- copy x -> h
__global__ __launch_bounds__(256) void copy_f32(const float* __restrict__ x,
                                                float* __restrict__ h, int n) {
    int i = blockIdx.x * 256 + threadIdx.x;
    if (i < n) h[i] = x[i];
}

// ---------------------------------------------------------------- weight transpose + cast
// in: fp32 [K,N] -> out: bf16 [N,K]
__global__ __launch_bounds__(256) void transpose_w(const float* __restrict__ in,
                                                   __bf16* __restrict__ out,
                                                   int K, int N) {
    __shared__ __bf16 tile[32][33];
    int n0 = blockIdx.x * 32, k0 = blockIdx.y * 32;
    int tx = threadIdx.x & 31, ty = threadIdx.x >> 5;
#pragma unroll
    for (int i = 0; i < 4; ++i) {
        int r = ty + i * 8;
        tile[r][tx] = (__bf16)in[(size_t)(k0 + r) * N + n0 + tx];
    }
    __syncthreads();
#pragma unroll
    for (int i = 0; i < 4; ++i) {
        int r = ty + i * 8;
        out[(size_t)(n0 + r) * K + k0 + tx] = tile[tx][r];
    }
}

// ---------------------------------------------------------------- LayerNorm (1024-wide rows)
template <typename T>
__global__ __launch_bounds__(256) void ln_kernel(const float* __restrict__ in,
                                                 const float* __restrict__ w,
                                                 const float* __restrict__ b,
                                                 T* __restrict__ out) {
    int row = blockIdx.x, tid = threadIdx.x;
    const float* x = in + (size_t)row * 1024;
    float v[4], s = 0.f, ss = 0.f;
#pragma unroll
    for (int i = 0; i < 4; i++) {
        v[i] = x[tid + i * 256];
        s += v[i];
        ss += v[i] * v[i];
    }
#pragma unroll
    for (int off = 32; off >= 1; off >>= 1) {
        s  += __shfl_xor(s, off, 64);
        ss += __shfl_xor(ss, off, 64);
    }
    __shared__ float ps[4], pss[4];
    int wid = tid >> 6, lane = tid & 63;
    if (lane == 0) { ps[wid] = s; pss[wid] = ss; }
    __syncthreads();
    s  = ps[0] + ps[1] + ps[2] + ps[3];
    ss = pss[0] + pss[1] + pss[2] + pss[3];
    float mean = s * (1.f / 1024.f);
    float var  = ss * (1.f / 1024.f) - mean * mean;
    float rstd = rsqrtf(var + 1e-5f);
    T* y = out + (size_t)row * 1024;
#pragma unroll
    for (int i = 0; i < 4; i++) {
        int c = tid + i * 256;
        y[c] = (T)((v[i] - mean) * rstd * w[c] + b[c]);
    }
}

// ---------------------------------------------------------------- bf16 MFMA GEMM
// C[M,N] = act( A[M,K] @ BT[N,K]^T + bias ) (+ resid). A,BT bf16; acc fp32.
// Tile MT x 128, BK=64, 256 threads = 4 waves, each wave (MT/2) x 64 via
// 16x16x32 MFMA. Fragment layouts per cdna4 guide (m89/m91-verified).
template <int MT, bool GELU_ACT, bool RESID, bool OUT_BF16>
__global__ __launch_bounds__(256) void gemm_bf16(const __bf16* __restrict__ A,
                                                 const __bf16* __restrict__ BT,
                                                 const float* __restrict__ bias,
                                                 const float* __restrict__ resid,
                                                 float* __restrict__ Cf,
                                                 __bf16* __restrict__ Cb,
                                                 int M, int N, int K) {
    constexpr int MI = MT / 32;  // m-tiles per wave
    __shared__ __align__(16) __bf16 As[MT][72];   // [m][k], pad 72 (36-dword stride)
    __shared__ __align__(16) __bf16 Bs[128][72];  // [n][k]
    const int tid = threadIdx.x;
    const int wave = tid >> 6, lane = tid & 63;
    const int quad = lane >> 4, l16 = lane & 15;
    const int wr = wave >> 1, wc = wave & 1;
    const int row0 = blockIdx.y * MT, col0 = blockIdx.x * 128;

    f32x4 acc[MI][4];
#pragma unroll
    for (int mi = 0; mi < MI; ++mi)
#pragma unroll
        for (int ni = 0; ni < 4; ++ni) acc[mi][ni] = (f32x4)0.f;

    for (int k0 = 0; k0 < K; k0 += 64) {
        __syncthreads();  // previous compute reads done before re-staging
#pragma unroll
        for (int i = 0; i < MT / 32; ++i) {
            int idx = tid + i * 256;
            int r = idx >> 3, kc = (idx & 7) * 8;
            *(float4*)&As[r][kc] = *(const float4*)&A[(size_t)(row0 + r) * K + k0 + kc];
        }
#pragma unroll
        for (int i = 0; i < 4; ++i) {
            int idx = tid + i * 256;
            int r = idx >> 3, kc = (idx & 7) * 8;
            *(float4*)&Bs[r][kc] = *(const float4*)&BT[(size_t)(col0 + r) * K + k0 + kc];
        }
        __syncthreads();
#pragma unroll
        for (int kk = 0; kk < 64; kk += 32) {
            bf16x8 af[MI], bfr[4];
#pragma unroll
            for (int mi = 0; mi < MI; ++mi)
                af[mi] = *(const bf16x8*)&As[wr * (MT / 2) + mi * 16 + l16][kk + quad * 8];
#pragma unroll
            for (int ni = 0; ni < 4; ++ni)
                bfr[ni] = *(const bf16x8*)&Bs[wc * 64 + ni * 16 + l16][kk + quad * 8];
#pragma unroll
            for (int mi = 0; mi < MI; ++mi)
#pragma unroll
                for (int ni = 0; ni < 4; ++ni)
                    acc[mi][ni] = __builtin_amdgcn_mfma_f32_16x16x32_bf16(
                        af[mi], bfr[ni], acc[mi][ni], 0, 0, 0);
        }
    }

#pragma unroll
    for (int mi = 0; mi < MI; ++mi) {
#pragma unroll
        for (int reg = 0; reg < 4; ++reg) {
            int m = row0 + wr * (MT / 2) + mi * 16 + quad * 4 + reg;
#pragma unroll
            for (int ni = 0; ni < 4; ++ni) {
                int n = col0 + wc * 64 + ni * 16 + l16;
                float v = acc[mi][ni][reg] + bias[n];
                if (GELU_ACT) v = 0.5f * v * (1.f + erff(v * 0.70710678118f));
                if (RESID) v += resid[(size_t)m * N + n];
                if (OUT_BF16) Cb[(size_t)m * N + n] = (__bf16)v;
                else          Cf[(size_t)m * N + n] = v;
            }
        }
    }
}

// ---------------------------------------------------------------- tiled flash attention
// One 256-thread block per (64-query tile, head, batch); fp32 qkv in, bf16 o out.
__global__ __launch_bounds__(256) void attn_tile_kernel(const float* __restrict__ qkv,
                                                        __bf16* __restrict__ o) {
    const int S = 1024;
    int bx = blockIdx.x;
    int h = blockIdx.y, b = blockIdx.z;
    int qt = (b == 0) ? (15 - bx) : bx;  // balance causal skew across CUs
    int tid = threadIdx.x;
    int tx = tid & 15, ty = tid >> 4;

    __shared__ __align__(16) float Qs[64][68];
    __shared__ __align__(16) float Ks[64][68];
    __shared__ __align__(16) float Vs[64][68];
    __shared__ __align__(16) float Ps[64][68];

    const float* base = qkv + (size_t)b * S * 3072 + h * 64;
    const float* qb = base;
    const float* kb = base + 1024;
    const float* vb = base + 2048;
    int q0 = qt * 64;

#pragma unroll
    for (int it = 0; it < 4; ++it) {
        int r = it * 16 + ty;
        float4 v = *(const float4*)&qb[(size_t)(q0 + r) * 3072 + tx * 4];
        Qs[tx * 4 + 0][r] = v.x * 0.125f;
        Qs[tx * 4 + 1][r] = v.y * 0.125f;
        Qs[tx * 4 + 2][r] = v.z * 0.125f;
        Qs[tx * 4 + 3][r] = v.w * 0.125f;
    }

    float m_i[4], l_i[4], O[4][4];
#pragma unroll
    for (int i = 0; i < 4; i++) {
        m_i[i] = -1e30f; l_i[i] = 0.f;
#pragma unroll
        for (int j = 0; j < 4; j++) O[i][j] = 0.f;
    }

    for (int c = 0; c <= qt; ++c) {
        int k0 = c * 64;
        __syncthreads();
#pragma unroll
        for (int it = 0; it < 4; ++it) {
            int r = it * 16 + ty;
            float4 kv = *(const float4*)&kb[(size_t)(k0 + r) * 3072 + tx * 4];
            Ks[tx * 4 + 0][r] = kv.x;
            Ks[tx * 4 + 1][r] = kv.y;
            Ks[tx * 4 + 2][r] = kv.z;
            Ks[tx * 4 + 3][r] = kv.w;
            float4 vv = *(const float4*)&vb[(size_t)(k0 + r) * 3072 + tx * 4];
            *(float4*)&Vs[r][tx * 4] = vv;
        }
        __syncthreads();

        float s[4][4] = {{0.f}};
#pragma unroll 16
        for (int d = 0; d < 64; ++d) {
            float4 a4 = *(const float4*)&Qs[d][ty * 4];
            float4 b4 = *(const float4*)&Ks[d][tx * 4];
            float a[4] = {a4.x, a4.y, a4.z, a4.w};
            float bb[4] = {b4.x, b4.y, b4.z, b4.w};
#pragma unroll
            for (int i = 0; i < 4; i++)
#pragma unroll
                for (int j = 0; j < 4; j++) s[i][j] += a[i] * bb[j];
        }
        if (c == qt) {
#pragma unroll
            for (int i = 0; i < 4; i++)
#pragma unroll
                for (int j = 0; j < 4; j++)
                    if (tx * 4 + j > ty * 4 + i) s[i][j] = -1e30f;
        }
        float alpha[4], p[4][4];
#pragma unroll
        for (int i = 0; i < 4; i++) {
            float mx = fmaxf(fmaxf(s[i][0], s[i][1]), fmaxf(s[i][2], s[i][3]));
#pragma unroll
            for (int off = 8; off >= 1; off >>= 1) mx = fmaxf(mx, __shfl_xor(mx, off, 64));
            float mnew = fmaxf(m_i[i], mx);
            alpha[i] = __expf(m_i[i] - mnew);
            float rs = 0.f;
#pragma unroll
            for (int j = 0; j < 4; j++) {
                p[i][j] = __expf(s[i][j] - mnew);
                if (s[i][j] <= -1e29f) p[i][j] = 0.f;
                rs += p[i][j];
            }
#pragma unroll
            for (int off = 8; off >= 1; off >>= 1) rs += __shfl_xor(rs, off, 64);
            l_i[i] = l_i[i] * alpha[i] + rs;
            m_i[i] = mnew;
        }
#pragma unroll
        for (int i = 0; i < 4; i++)
#pragma unroll
            for (int j = 0; j < 4; j++)
                Ps[tx * 4 + j][ty * 4 + i] = p[i][j];
#pragma unroll
        for (int i = 0; i < 4; i++)
#pragma unroll
            for (int j = 0; j < 4; j++) O[i][j] *= alpha[i];
        __syncthreads();
#pragma unroll 16
        for (int k = 0; k < 64; ++k) {
            float4 a4 = *(const float4*)&Ps[k][ty * 4];
            float4 b4 = *(const float4*)&Vs[k][tx * 4];
            float a[4] = {a4.x, a4.y, a4.z, a4.w};
            float bb[4] = {b4.x, b4.y, b4.z, b4.w};
#pragma unroll
            for (int i = 0; i < 4; i++)
#pragma unroll
                for (int j = 0; j < 4; j++) O[i][j] += a[i] * bb[j];
        }
    }

#pragma unroll
    for (int i = 0; i < 4; i++) {
        float inv = 1.f / l_i[i];
        int q = q0 + ty * 4 + i;
        bf16x4 v;
        v[0] = (__bf16)(O[i][0] * inv);
        v[1] = (__bf16)(O[i][1] * inv);
        v[2] = (__bf16)(O[i][2] * inv);
        v[3] = (__bf16)(O[i][3] * inv);
        *(bf16x4*)&o[((size_t)b * S + q) * 1024 + h * 64 + tx * 4] = v;
    }
}

// ---------------------------------------------------------------- final projection to WIN=5
__global__ __launch_bounds__(64) void proj_kernel(const float* __restrict__ hn,
                                                  const float* __restrict__ Wp,
                                                  const float* __restrict__ bp,
                                                  float* __restrict__ out) {
    int t = blockIdx.x, lane = threadIdx.x;
    const float* x = hn + (size_t)t * 1024;
    float acc[5] = {0.f, 0.f, 0.f, 0.f, 0.f};
    for (int d = lane; d < 1024; d += 64) {
        float xv = x[d];
#pragma unroll
        for (int j = 0; j < 5; j++) acc[j] += xv * Wp[d * 5 + j];
    }
#pragma unroll
    for (int j = 0; j < 5; j++)
#pragma unroll
        for (int off = 32; off >= 1; off >>= 1) acc[j] += __shfl_xor(acc[j], off, 64);
    if (lane == 0) {
#pragma unroll
        for (int j = 0; j < 5; j++)
            out[(size_t)t * 5 + j] = acc[j] + bp[j];
    }
}

// ---------------------------------------------------------------- launch
extern "C" void kernel_launch(void* const* d_in, const int* in_sizes, int n_in,
                              void* d_out, int out_size, void* d_ws, size_t ws_size,
                              hipStream_t stream) {
    const float* x    = (const float*)d_in[0];
    const float* Wqkv = (const float*)d_in[1];
    const float* bqkv = (const float*)d_in[2];
    const float* Wo   = (const float*)d_in[3];
    const float* bo   = (const float*)d_in[4];
    const float* ln1w = (const float*)d_in[5];
    const float* ln1b = (const float*)d_in[6];
    const float* W1   = (const float*)d_in[7];
    const float* b1   = (const float*)d_in[8];
    const float* W2   = (const float*)d_in[9];
    const float* b2   = (const float*)d_in[10];
    const float* ln2w = (const float*)d_in[11];
    const float* ln2b = (const float*)d_in[12];
    const float* lnfw = (const float*)d_in[13];
    const float* lnfb = (const float*)d_in[14];
    const float* Wp   = (const float*)d_in[15];
    const float* bp   = (const float*)d_in[16];
    float* out = (float*)d_out;

    // workspace layout (~81 MB)
    char* p = (char*)d_ws;
    float*  h    = (float*)p;  p += (size_t)2097152 * 4;   // residual stream fp32
    __bf16* hn_b = (__bf16*)p; p += (size_t)2097152 * 2;   // LN output bf16
    float*  qkv  = (float*)p;  p += (size_t)6291456 * 4;   // qkv fp32 (reused as lnf fp32 out)
    __bf16* o_b  = (__bf16*)p; p += (size_t)2097152 * 2;   // attention out bf16
    __bf16* ff_b = (__bf16*)p; p += (size_t)8388608 * 2;   // FFN mid bf16
    __bf16* wT   = (__bf16*)p;                              // per-layer transposed weights
    __bf16* wqkvT = wT;                 // [3072][1024]
    __bf16* woT   = wqkvT + 3145728;    // [1024][1024]
    __bf16* w1T   = woT   + 1048576;    // [4096][1024]
    __bf16* w2T   = w1T   + 4194304;    // [1024][4096]

    copy_f32<<<8192, 256, 0, stream>>>(x, h, 2097152);

    for (int l = 0; l < 6; ++l) {
        transpose_w<<<dim3(96, 32), 256, 0, stream>>>(Wqkv + (size_t)l * 3145728, wqkvT, 1024, 3072);
        transpose_w<<<dim3(32, 32), 256, 0, stream>>>(Wo   + (size_t)l * 1048576, woT,   1024, 1024);
        transpose_w<<<dim3(128, 32), 256, 0, stream>>>(W1  + (size_t)l * 4194304, w1T,   1024, 4096);
        transpose_w<<<dim3(32, 128), 256, 0, stream>>>(W2  + (size_t)l * 4194304, w2T,   4096, 1024);

        ln_kernel<__bf16><<<2048, 256, 0, stream>>>(h, ln1w + l * 1024, ln1b + l * 1024, hn_b);
        gemm_bf16<128, false, false, false><<<dim3(24, 16), 256, 0, stream>>>(
            hn_b, wqkvT, bqkv + l * 3072, nullptr, qkv, nullptr, 2048, 3072, 1024);
        attn_tile_kernel<<<dim3(16, 16, 2), 256, 0, stream>>>(qkv, o_b);
        gemm_bf16<64, false, true, false><<<dim3(8, 32), 256, 0, stream>>>(
            o_b, woT, bo + l * 1024, h, h, nullptr, 2048, 1024, 1024);
        ln_kernel<__bf16><<<2048, 256, 0, stream>>>(h, ln2w + l * 1024, ln2b + l * 1024, hn_b);
        gemm_bf16<128, true, false, true><<<dim3(32, 16), 256, 0, stream>>>(
            hn_b, w1T, b1 + l * 4096, nullptr, nullptr, ff_b, 2048, 4096, 1024);
        gemm_bf16<64, false, true, false><<<dim3(8, 32), 256, 0, stream>>>(
            ff_b, w2T, b2 + l * 1024, h, h, nullptr, 2048, 1024, 4096);
    }
    float* hn_f = qkv;  // reuse qkv buffer for lnf output (fp32)
    ln_kernel<float><<<2048, 256, 0, stream>>>(h, lnfw, lnfb, hn_f);
    proj_kernel<<<2048, 64, 0, stream>>>(hn_f, Wp, bp, out);
}